// Round 4
// baseline (205.134 us; speedup 1.0000x reference)
//
#include <hip/hip_runtime.h>
#include <math.h>

// Problem constants
#define B_   2
#define S_   256
#define E_   512
#define H_   8
#define DH_  64
#define LTOT   8192   // total KV rows per batch (TC*H + S*H)
#define LCACHE 6144   // TC*H
#define LNEW   2048   // S*H

#define QSCALE (0.125f * 1.44269504088896f)   // 1/sqrt(DH) * log2(e)

typedef __attribute__((ext_vector_type(8))) short bf16x8;
typedef __attribute__((ext_vector_type(4))) float f32x4;

__device__ __forceinline__ ushort f2bf(float f) {             // RTN f32->bf16
    unsigned u = __float_as_uint(f);
    return (ushort)((u + 0x7fffu + ((u >> 16) & 1u)) >> 16);
}
__device__ __forceinline__ void split_hilo(float v, ushort& h, ushort& l) {
    h = f2bf(v);
    l = f2bf(v - __uint_as_float((unsigned)h << 16));
}

// ---------------------------------------------------------------------------
// prep_all: one kernel, three block-uniform paths.
//   bx <160 : fp32->bf16 hi/lo for {x, Wq, Wk, Wv, Wo}   (32 blocks each)
//   bx <256 : K cache fp32 -> Khi/Klo rows 0..6143        (48 blocks x B)
//   bx <448 : V cache fp32 -> Vt bf16 [B][64][8192] cols 0..6143 (96 x B)
// ---------------------------------------------------------------------------
__global__ __launch_bounds__(256) void prep_all(
    const float* __restrict__ x,  const float* __restrict__ Wq,
    const float* __restrict__ Wk, const float* __restrict__ Wv,
    const float* __restrict__ Wo, const float* __restrict__ Kc,
    const float* __restrict__ Vc,
    ushort* __restrict__ xh,  ushort* __restrict__ xl,
    ushort* __restrict__ Wqh, ushort* __restrict__ Wql,
    ushort* __restrict__ Wkh, ushort* __restrict__ Wkl,
    ushort* __restrict__ Wvh, ushort* __restrict__ Wvl,
    ushort* __restrict__ Woh, ushort* __restrict__ Wol,
    ushort* __restrict__ Khi, ushort* __restrict__ Klo,
    ushort* __restrict__ Vt)
{
    __shared__ ushort sT[64][68];
    const int bx = blockIdx.x, tid = threadIdx.x;

    if (bx < 160) {
        const int z = bx >> 5;
        const float* src; ushort* dh; ushort* dl;
        if (z == 0)      { src = x;  dh = xh;  dl = xl;  }
        else if (z == 1) { src = Wq; dh = Wqh; dl = Wql; }
        else if (z == 2) { src = Wk; dh = Wkh; dl = Wkl; }
        else if (z == 3) { src = Wv; dh = Wvh; dl = Wvl; }
        else             { src = Wo; dh = Woh; dl = Wol; }
        for (int i = (bx & 31) * 256 + tid; i < 65536; i += 32 * 256) {
            const float4 v = reinterpret_cast<const float4*>(src)[i];
            ushort4 h, l;
            split_hilo(v.x, h.x, l.x); split_hilo(v.y, h.y, l.y);
            split_hilo(v.z, h.z, l.z); split_hilo(v.w, h.w, l.w);
            reinterpret_cast<ushort4*>(dh)[i] = h;
            reinterpret_cast<ushort4*>(dl)[i] = l;
        }
    } else if (bx < 256) {
        const int idx = bx - 160;
        const int b = idx / 48, blk = idx % 48;
        const float* src = Kc + (size_t)b * 393216;
        ushort* dh = Khi + (size_t)b * 524288;
        ushort* dl = Klo + (size_t)b * 524288;
        for (int i = blk * 256 + tid; i < 98304; i += 48 * 256) {
            const float4 v = reinterpret_cast<const float4*>(src)[i];
            ushort4 h, l;
            split_hilo(v.x, h.x, l.x); split_hilo(v.y, h.y, l.y);
            split_hilo(v.z, h.z, l.z); split_hilo(v.w, h.w, l.w);
            reinterpret_cast<ushort4*>(dh)[i] = h;
            reinterpret_cast<ushort4*>(dl)[i] = l;
        }
    } else {
        const int idx = bx - 256;
        const int b = idx / 96, kt = idx % 96;
        const int key0 = kt * 64;
#pragma unroll
        for (int it = 0; it < 4; ++it) {
            const int id = it * 256 + tid;
            const int row = id >> 4, c4 = (id & 15) << 2;
            const float4 v = *reinterpret_cast<const float4*>(
                &Vc[((size_t)b * LCACHE + key0 + row) * 64 + c4]);
            sT[c4+0][row] = f2bf(v.x); sT[c4+1][row] = f2bf(v.y);
            sT[c4+2][row] = f2bf(v.z); sT[c4+3][row] = f2bf(v.w);
        }
        __syncthreads();
#pragma unroll
        for (int it = 0; it < 4; ++it) {
            const int id = it * 256 + tid;
            const int d = id >> 4, ku = (id & 15) << 2;
            ushort4 o;
            o.x = sT[d][ku]; o.y = sT[d][ku+1]; o.z = sT[d][ku+2]; o.w = sT[d][ku+3];
            *reinterpret_cast<ushort4*>(&Vt[((size_t)b * 64 + d) * LTOT + key0 + ku]) = o;
        }
    }
}

// ---------------------------------------------------------------------------
// proj_body: MFMA NT GEMM, C = x @ W^T + bias, 512^3, bf16 hi/lo 3-term.
// A = W rows (output dim), B = x rows (token). D: col=lane&15 -> token.
// mode 0: Q  (x QSCALE, hi/lo -> dh/dl, [b][2048][64] flat)
// mode 1: K  (hi/lo -> rows 6144.. of [b][8192][64])
// mode 2: V  (bf16 directly TRANSPOSED into Vt cols 6144..8191)
// mode 3: O  (fp32 -> df [512][512])
// ---------------------------------------------------------------------------
__device__ __forceinline__ void proj_body(
    const ushort* __restrict__ Ah, const ushort* __restrict__ Al,
    const ushort* __restrict__ Bh, const ushort* __restrict__ Bl,
    const float* __restrict__ bias, const int mode,
    ushort* __restrict__ dh, ushort* __restrict__ dl, float* __restrict__ df)
{
    const int tid = threadIdx.x;
    const int wv = tid >> 6, lane = tid & 63;
    const int lr = lane & 15, lg = lane >> 4;
    const int m0 = blockIdx.y * 64 + (wv & 1) * 32;   // token base
    const int n0 = blockIdx.x * 64 + (wv >> 1) * 32;  // output-dim base

    f32x4 acc[2][2];
#pragma unroll
    for (int mi = 0; mi < 2; ++mi)
#pragma unroll
        for (int ni = 0; ni < 2; ++ni) acc[mi][ni] = (f32x4){0.f, 0.f, 0.f, 0.f};

    const ushort* pa[2] = { Ah + (size_t)(n0 + lr) * 512 + lg * 8,
                            Ah + (size_t)(n0 + 16 + lr) * 512 + lg * 8 };
    const ushort* qa[2] = { Al + (size_t)(n0 + lr) * 512 + lg * 8,
                            Al + (size_t)(n0 + 16 + lr) * 512 + lg * 8 };
    const ushort* pb[2] = { Bh + (size_t)(m0 + lr) * 512 + lg * 8,
                            Bh + (size_t)(m0 + 16 + lr) * 512 + lg * 8 };
    const ushort* qb[2] = { Bl + (size_t)(m0 + lr) * 512 + lg * 8,
                            Bl + (size_t)(m0 + 16 + lr) * 512 + lg * 8 };

#pragma unroll 4
    for (int k0 = 0; k0 < 512; k0 += 32) {
        bf16x8 ah[2], al[2], bh[2], bl[2];
#pragma unroll
        for (int t = 0; t < 2; ++t) {
            ah[t] = *reinterpret_cast<const bf16x8*>(pa[t] + k0);
            al[t] = *reinterpret_cast<const bf16x8*>(qa[t] + k0);
            bh[t] = *reinterpret_cast<const bf16x8*>(pb[t] + k0);
            bl[t] = *reinterpret_cast<const bf16x8*>(qb[t] + k0);
        }
#pragma unroll
        for (int mi = 0; mi < 2; ++mi)
#pragma unroll
            for (int ni = 0; ni < 2; ++ni) {
                acc[mi][ni] = __builtin_amdgcn_mfma_f32_16x16x32_bf16(ah[ni], bh[mi], acc[mi][ni], 0, 0, 0);
                acc[mi][ni] = __builtin_amdgcn_mfma_f32_16x16x32_bf16(ah[ni], bl[mi], acc[mi][ni], 0, 0, 0);
                acc[mi][ni] = __builtin_amdgcn_mfma_f32_16x16x32_bf16(al[ni], bh[mi], acc[mi][ni], 0, 0, 0);
            }
    }

#pragma unroll
    for (int mi = 0; mi < 2; ++mi)
#pragma unroll
        for (int ni = 0; ni < 2; ++ni) {
            const int tok = m0 + mi * 16 + lr;
            const int e   = n0 + ni * 16 + lg * 4;
            const float4 bb = *reinterpret_cast<const float4*>(&bias[e]);
            float v0 = acc[mi][ni].x + bb.x, v1 = acc[mi][ni].y + bb.y;
            float v2 = acc[mi][ni].z + bb.z, v3 = acc[mi][ni].w + bb.w;
            const int b = tok >> 8, s = tok & 255;
            if (mode == 0) {
                v0 *= QSCALE; v1 *= QSCALE; v2 *= QSCALE; v3 *= QSCALE;
                ushort4 h, l;
                split_hilo(v0, h.x, l.x); split_hilo(v1, h.y, l.y);
                split_hilo(v2, h.z, l.z); split_hilo(v3, h.w, l.w);
                const size_t off = (size_t)b * 131072 + s * 512 + e;
                *reinterpret_cast<ushort4*>(dh + off) = h;
                *reinterpret_cast<ushort4*>(dl + off) = l;
            } else if (mode == 1) {
                ushort4 h, l;
                split_hilo(v0, h.x, l.x); split_hilo(v1, h.y, l.y);
                split_hilo(v2, h.z, l.z); split_hilo(v3, h.w, l.w);
                const size_t off = (size_t)b * 524288 + 393216 + s * 512 + e;
                *reinterpret_cast<ushort4*>(dh + off) = h;
                *reinterpret_cast<ushort4*>(dl + off) = l;
            } else if (mode == 2) {
                // transpose directly into Vt: dim = e&63 (+j), key = 6144+s*8+h
                const int hh = e >> 6, dhd = e & 63;
                const size_t col = 6144 + s * 8 + hh;
                ushort* vb = dh + ((size_t)b * 64 + dhd) * LTOT + col;
                vb[0 * LTOT] = f2bf(v0); vb[1 * LTOT] = f2bf(v1);
                vb[2 * LTOT] = f2bf(v2); vb[3 * LTOT] = f2bf(v3);
            } else {
                float4 o; o.x = v0; o.y = v1; o.z = v2; o.w = v3;
                *reinterpret_cast<float4*>(df + (size_t)tok * 512 + e) = o;
            }
        }
}

__global__ __launch_bounds__(256) void proj_qkv_mfma(
    const ushort* __restrict__ Wqh, const ushort* __restrict__ Wql,
    const ushort* __restrict__ Wkh, const ushort* __restrict__ Wkl,
    const ushort* __restrict__ Wvh, const ushort* __restrict__ Wvl,
    const ushort* __restrict__ xh,  const ushort* __restrict__ xl,
    const float* __restrict__ bq, const float* __restrict__ bk, const float* __restrict__ bv,
    ushort* __restrict__ Qhi, ushort* __restrict__ Qlo,
    ushort* __restrict__ Khi, ushort* __restrict__ Klo,
    ushort* __restrict__ Vt)
{
    if (blockIdx.z == 0)      proj_body(Wqh, Wql, xh, xl, bq, 0, Qhi, Qlo, nullptr);
    else if (blockIdx.z == 1) proj_body(Wkh, Wkl, xh, xl, bk, 1, Khi, Klo, nullptr);
    else                      proj_body(Wvh, Wvl, xh, xl, bv, 2, Vt, nullptr, nullptr);
}

__global__ __launch_bounds__(256) void proj_o_mfma(
    const ushort* __restrict__ Woh, const ushort* __restrict__ Wol,
    const ushort* __restrict__ Aoh, const ushort* __restrict__ Aol,
    const float* __restrict__ bo, float* __restrict__ out)
{
    proj_body(Woh, Wol, Aoh, Aol, bo, 3, nullptr, nullptr, out);
}

// ---------------------------------------------------------------------------
// attn_mfma: flash attention, no L-split. 256 blocks x 512 thr (8 waves).
// Block owns 16 q-rows; wave wv owns keys [wv*1024, wv*1024+1024).
// Register double-buffered prefetch of K(hi/lo)/V^T fragments.
// In-block LDS combine across the 8 waves -> Ao (bf16 hi/lo) directly.
// ---------------------------------------------------------------------------
#define LOADT(kf, lf, vf, t) do {                                                   \
    _Pragma("unroll")                                                               \
    for (int st = 0; st < 2; ++st) {                                                \
        _Pragma("unroll")                                                           \
        for (int h = 0; h < 2; ++h) {                                               \
            kf[st][h] = *reinterpret_cast<const bf16x8*>(kh_p + (t) * 2048 + st * 256 + h * 32); \
            lf[st][h] = *reinterpret_cast<const bf16x8*>(kl_p + (t) * 2048 + st * 256 + h * 32); \
        }                                                                           \
    }                                                                               \
    _Pragma("unroll")                                                               \
    for (int dt = 0; dt < 4; ++dt)                                                  \
        vf[dt] = *reinterpret_cast<const bf16x8*>(vt_p + dt * 131072 + (t) * 32);   \
} while (0)

#define COMPUTE(kf, lf, vf) do {                                                    \
    f32x4 s0 = {0.f,0.f,0.f,0.f}, s1 = {0.f,0.f,0.f,0.f};                           \
    __builtin_amdgcn_s_setprio(1);                                                  \
    _Pragma("unroll")                                                               \
    for (int h = 0; h < 2; ++h) {                                                   \
        s0 = __builtin_amdgcn_mfma_f32_16x16x32_bf16(kf[0][h], qh[h], s0, 0, 0, 0); \
        s0 = __builtin_amdgcn_mfma_f32_16x16x32_bf16(kf[0][h], ql[h], s0, 0, 0, 0); \
        s0 = __builtin_amdgcn_mfma_f32_16x16x32_bf16(lf[0][h], qh[h], s0, 0, 0, 0); \
        s1 = __builtin_amdgcn_mfma_f32_16x16x32_bf16(kf[1][h], qh[h], s1, 0, 0, 0); \
        s1 = __builtin_amdgcn_mfma_f32_16x16x32_bf16(kf[1][h], ql[h], s1, 0, 0, 0); \
        s1 = __builtin_amdgcn_mfma_f32_16x16x32_bf16(lf[1][h], qh[h], s1, 0, 0, 0); \
    }                                                                               \
    __builtin_amdgcn_s_setprio(0);                                                  \
    float tm = fmaxf(fmaxf(fmaxf(s0.x, s0.y), fmaxf(s0.z, s0.w)),                   \
                     fmaxf(fmaxf(s1.x, s1.y), fmaxf(s1.z, s1.w)));                  \
    tm = fmaxf(tm, __shfl_xor(tm, 16));                                             \
    tm = fmaxf(tm, __shfl_xor(tm, 32));                                             \
    const float mn = fmaxf(m, tm);                                                  \
    const float corr = __builtin_exp2f(m - mn);                                     \
    float p[8];                                                                     \
    p[0] = __builtin_exp2f(s0.x - mn); p[1] = __builtin_exp2f(s0.y - mn);           \
    p[2] = __builtin_exp2f(s0.z - mn); p[3] = __builtin_exp2f(s0.w - mn);           \
    p[4] = __builtin_exp2f(s1.x - mn); p[5] = __builtin_exp2f(s1.y - mn);           \
    p[6] = __builtin_exp2f(s1.z - mn); p[7] = __builtin_exp2f(s1.w - mn);           \
    float ps = ((p[0]+p[1]) + (p[2]+p[3])) + ((p[4]+p[5]) + (p[6]+p[7]));           \
    ps += __shfl_xor(ps, 16);                                                       \
    ps += __shfl_xor(ps, 32);                                                       \
    l = l * corr + ps; m = mn;                                                      \
    union { bf16x8 v; ushort u[8]; } pf;                                            \
    _Pragma("unroll")                                                               \
    for (int j = 0; j < 8; ++j) pf.u[j] = f2bf(p[j]);                               \
    __builtin_amdgcn_s_setprio(1);                                                  \
    _Pragma("unroll")                                                               \
    for (int dt = 0; dt < 4; ++dt) {                                                \
        f32x4 a = acc[dt];                                                          \
        a.x *= corr; a.y *= corr; a.z *= corr; a.w *= corr;                         \
        acc[dt] = __builtin_amdgcn_mfma_f32_16x16x32_bf16(vf[dt], pf.v, a, 0, 0, 0);\
    }                                                                               \
    __builtin_amdgcn_s_setprio(0);                                                  \
} while (0)

__global__ __launch_bounds__(512) void attn_mfma(
    const ushort* __restrict__ Qhi, const ushort* __restrict__ Qlo,
    const ushort* __restrict__ Khi, const ushort* __restrict__ Klo,
    const ushort* __restrict__ Vt,
    ushort* __restrict__ Aoh, ushort* __restrict__ Aol)
{
    __shared__ float sAcc[8][16][68];
    __shared__ float sM[8][16];
    __shared__ float sL[8][16];

    const int tid = threadIdx.x;
    const int wv = tid >> 6, lane = tid & 63;
    const int lr = lane & 15, lg = lane >> 4;
    const int qb = blockIdx.x & 127, b = blockIdx.x >> 7;

    // Q fragments (Q pre-scaled by QSCALE in projection)
    bf16x8 qh[2], ql[2];
    {
        const int qrow0 = b * 2048 + qb * 16 + lr;
#pragma unroll
        for (int h = 0; h < 2; ++h) {
            const int off = qrow0 * 64 + h * 32 + lg * 8;
            qh[h] = *reinterpret_cast<const bf16x8*>(Qhi + off);
            ql[h] = *reinterpret_cast<const bf16x8*>(Qlo + off);
        }
    }

    const int kbase = wv * 1024;                               // 1024 keys/wave
    const int krow0 = kbase + (lr & 3) + ((lr >> 2) << 3);     // permuted A row
    const ushort* kh_p = Khi + (size_t)b * 524288 + (size_t)krow0 * 64 + lg * 8;
    const ushort* kl_p = Klo + (size_t)b * 524288 + (size_t)krow0 * 64 + lg * 8;
    const ushort* vt_p = Vt  + (size_t)b * 524288 + (size_t)lr * LTOT + kbase + lg * 8;

    f32x4 acc[4];
#pragma unroll
    for (int dt = 0; dt < 4; ++dt) acc[dt] = (f32x4){0.f, 0.f, 0.f, 0.f};
    float m = -INFINITY, l = 0.f;

    bf16x8 kfA[2][2], lfA[2][2], vfA[4];
    bf16x8 kfB[2][2], lfB[2][2], vfB[4];

    LOADT(kfA, lfA, vfA, 0);
    for (int tt = 0; tt < 16; ++tt) {                          // 32 tiles, 2/iter
        LOADT(kfB, lfB, vfB, 2 * tt + 1);
        COMPUTE(kfA, lfA, vfA);
        if (tt < 15) LOADT(kfA, lfA, vfA, 2 * tt + 2);
        COMPUTE(kfB, lfB, vfB);
    }

    // per-wave partials -> LDS   (C/D: col=lane&15 -> qrow, rows -> dims)
#pragma unroll
    for (int dt = 0; dt < 4; ++dt) {
        float4 o; o.x = acc[dt].x; o.y = acc[dt].y; o.z = acc[dt].z; o.w = acc[dt].w;
        *reinterpret_cast<float4*>(&sAcc[wv][lr][dt * 16 + lg * 4]) = o;
    }
    if (lg == 0) { sM[wv][lr] = m; sL[wv][lr] = l; }
    __syncthreads();

    // combine 8 waves: thread -> (qrow = tid>>5, 2 dims at d0 = (tid&31)*2)
    {
        const int row = tid >> 5, d0 = (tid & 31) * 2;
        float ms = -INFINITY;
#pragma unroll
        for (int w = 0; w < 8; ++w) ms = fmaxf(ms, sM[w][row]);
        float den = 0.f, n0 = 0.f, n1 = 0.f;
#pragma unroll
        for (int w = 0; w < 8; ++w) {
            const float e = __builtin_exp2f(sM[w][row] - ms);
            den = fmaf(sL[w][row], e, den);
            const float2 a = *reinterpret_cast<const float2*>(&sAcc[w][row][d0]);
            n0 = fmaf(a.x, e, n0);
            n1 = fmaf(a.y, e, n1);
        }
        const float inv = 1.0f / den;
        const float v0 = n0 * inv, v1 = n1 * inv;
        ushort h0, l0u, h1, l1u;
        split_hilo(v0, h0, l0u); split_hilo(v1, h1, l1u);
        const size_t o = ((size_t)(b * 2048 + qb * 16 + row)) * 64 + d0;
        ushort2 ho; ho.x = h0; ho.y = h1;
        ushort2 lo; lo.x = l0u; lo.y = l1u;
        *reinterpret_cast<ushort2*>(Aoh + o) = ho;
        *reinterpret_cast<ushort2*>(Aol + o) = lo;
    }
}

// ---------------------------------------------------------------------------
extern "C" void kernel_launch(void* const* d_in, const int* in_sizes, int n_in,
                              void* d_out, int out_size, void* d_ws, size_t ws_size,
                              hipStream_t stream)
{
    const float* x  = (const float*)d_in[0];
    const float* kc = (const float*)d_in[1];
    const float* vc = (const float*)d_in[2];
    const float* Wq = (const float*)d_in[3];
    const float* bq = (const float*)d_in[4];
    const float* Wk = (const float*)d_in[5];
    const float* bk = (const float*)d_in[6];
    const float* Wv = (const float*)d_in[7];
    const float* bv = (const float*)d_in[8];
    const float* Wo = (const float*)d_in[9];
    const float* bo = (const float*)d_in[10];
    float* out = (float*)d_out;

    ushort* us  = (ushort*)d_ws;
    ushort* Khi = us;                   // 1048576
    ushort* Klo = us + 1048576;         // 1048576
    ushort* Vt  = us + 2097152;         // 1048576
    ushort* Qhi = us + 3145728;         //  262144
    ushort* Qlo = us + 3407872;         //  262144
    ushort* xh  = us + 3670016;         //  262144
    ushort* xl  = us + 3932160;         //  262144
    ushort* Wqh = us + 4194304;         //  262144
    ushort* Wql = us + 4456448;
    ushort* Wkh = us + 4718592;
    ushort* Wkl = us + 4980736;
    ushort* Wvh = us + 5242880;
    ushort* Wvl = us + 5505024;
    ushort* Woh = us + 5767168;
    ushort* Wol = us + 6029312;
    ushort* Aoh = us + 6291456;         //  262144
    ushort* Aol = us + 6553600;         //  262144 -> ends 6815744 us (13.6 MB)

    // 1. prep: hi/lo conversions + K-cache hi/lo + V-cache transpose
    prep_all<<<dim3(448), 256, 0, stream>>>(
        x, Wq, Wk, Wv, Wo, kc, vc,
        xh, xl, Wqh, Wql, Wkh, Wkl, Wvh, Wvl, Woh, Wol, Khi, Klo, Vt);

    // 2. QKV projections (MFMA) -> Qhi/Qlo, Khi/Klo rows 6144.., Vt cols 6144..
    proj_qkv_mfma<<<dim3(8, 8, 3), 256, 0, stream>>>(
        Wqh, Wql, Wkh, Wkl, Wvh, Wvl, xh, xl, bq, bk, bv, Qhi, Qlo, Khi, Klo, Vt);

    // 3. Flash attention (no split, in-block combine) -> Ao bf16 hi/lo
    attn_mfma<<<dim3(256), 512, 0, stream>>>(Qhi, Qlo, Khi, Klo, Vt, Aoh, Aol);

    // 4. Output projection (MFMA) -> fp32 out
    proj_o_mfma<<<dim3(8, 8), 256, 0, stream>>>(Woh, Wol, Aoh, Aol, bo, out);
}

// Round 6
// 135.639 us; speedup vs baseline: 1.5123x; 1.5123x over previous
//
#include <hip/hip_runtime.h>
#include <math.h>

// Problem constants
#define B_   2
#define LTOT   8192   // total KV rows per batch
#define LCACHE 6144   // cached KV rows
#define LNEW   2048   // new KV rows (S*H)
#define NSPLIT 4

#define QSCALE (0.125f * 1.44269504088896f)   // 1/sqrt(64) * log2(e)

typedef __attribute__((ext_vector_type(8))) short bf16x8;
typedef __attribute__((ext_vector_type(4))) float f32x4;

__device__ __forceinline__ ushort f2bf(float f) {             // RTN f32->bf16
    unsigned u = __float_as_uint(f);
    return (ushort)((u + 0x7fffu + ((u >> 16) & 1u)) >> 16);
}
__device__ __forceinline__ void split_hilo(float v, ushort& h, ushort& l) {
    h = f2bf(v);
    l = f2bf(v - __uint_as_float((unsigned)h << 16));
}

// ---------------------------------------------------------------------------
// Fragment-major layouts (all reads in MFMA loops are lane-contiguous 16B):
//
// GEMM frag (x, W*, Ao; 512x512 tensors, hi/lo pairs):
//   flat = R*8192 + kk*512 + lane*8 + j
//   holds T[row = R*16 + (lane&15)][col = kk*32 + (lane>>4)*8 + j]
//
// K swizzled (per batch, base b*524288), 32-key tiles:
//   flat = T*2048 + st*1024 + h*512 + lane*8 + j
//   holds K[key = T*32 + st*4 + (lr&3) + (lr>>2)*8][e = h*32 + lg*8 + j]
//   where lr = lane&15, lg = lane>>4   (the QK^T A-fragment permutation)
//
// V^T swizzled (per batch, base b*524288), 32-key tiles:
//   flat = T*2048 + dt*512 + lane*8 + j
//   holds V[key = T*32 + lg*8 + j][d = dt*16 + lr]
// ---------------------------------------------------------------------------

// ---------------------------------------------------------------------------
// prep_all: 448 blocks x 256.
//   bx<160 : {x,Wq,Wk,Wv,Wo} fp32 -> hi/lo GEMM-frag layout (32 blocks each)
//   bx<256 : K cache -> Khi/Klo swizzled, keys 0..6143 (48 x B)
//   bx<448 : V cache -> VtS swizzled, keys 0..6143     (96 x B)
// ---------------------------------------------------------------------------
__global__ __launch_bounds__(256) void prep_all(
    const float* __restrict__ x,  const float* __restrict__ Wq,
    const float* __restrict__ Wk, const float* __restrict__ Wv,
    const float* __restrict__ Wo, const float* __restrict__ Kc,
    const float* __restrict__ Vc,
    ushort* __restrict__ xh,  ushort* __restrict__ xl,
    ushort* __restrict__ Wqh, ushort* __restrict__ Wql,
    ushort* __restrict__ Wkh, ushort* __restrict__ Wkl,
    ushort* __restrict__ Wvh, ushort* __restrict__ Wvl,
    ushort* __restrict__ Woh, ushort* __restrict__ Wol,
    ushort* __restrict__ Khi, ushort* __restrict__ Klo,
    ushort* __restrict__ VtS)
{
    __shared__ ushort sT[64][68];
    const int bx = blockIdx.x, tid = threadIdx.x;

    if (bx < 160) {
        const int z = bx >> 5;
        const float* src; ushort* dh; ushort* dl;
        if (z == 0)      { src = x;  dh = xh;  dl = xl;  }
        else if (z == 1) { src = Wq; dh = Wqh; dl = Wql; }
        else if (z == 2) { src = Wk; dh = Wkh; dl = Wkl; }
        else if (z == 3) { src = Wv; dh = Wvh; dl = Wvl; }
        else             { src = Wo; dh = Woh; dl = Wol; }
        const int idx0 = (bx & 31) * 256 + tid;
#pragma unroll
        for (int it = 0; it < 4; ++it) {
            const int slot = idx0 + it * 8192;                // 0..32767
            const int R = slot >> 10, kk = (slot >> 6) & 15, ln = slot & 63;
            const int row = R * 16 + (ln & 15), col = kk * 32 + (ln >> 4) * 8;
            const float4 a = *reinterpret_cast<const float4*>(src + row * 512 + col);
            const float4 b4 = *reinterpret_cast<const float4*>(src + row * 512 + col + 4);
            ushort4 h0, l0, h1, l1;
            split_hilo(a.x,  h0.x, l0.x); split_hilo(a.y,  h0.y, l0.y);
            split_hilo(a.z,  h0.z, l0.z); split_hilo(a.w,  h0.w, l0.w);
            split_hilo(b4.x, h1.x, l1.x); split_hilo(b4.y, h1.y, l1.y);
            split_hilo(b4.z, h1.z, l1.z); split_hilo(b4.w, h1.w, l1.w);
            *reinterpret_cast<ushort4*>(dh + slot * 8)     = h0;
            *reinterpret_cast<ushort4*>(dh + slot * 8 + 4) = h1;
            *reinterpret_cast<ushort4*>(dl + slot * 8)     = l0;
            *reinterpret_cast<ushort4*>(dl + slot * 8 + 4) = l1;
        }
    } else if (bx < 256) {
        const int idx = bx - 160;
        const int b = idx / 48, blk = idx % 48;
        const int idx0 = blk * 256 + tid;
#pragma unroll
        for (int it = 0; it < 4; ++it) {
            const int slot = idx0 + it * 12288;               // 0..49151
            const int key = slot >> 3, g = slot & 7;
            const int h = g >> 2, lg = g & 3;
            const float* src = Kc + ((size_t)b * LCACHE + key) * 64 + g * 8;
            const float4 a = *reinterpret_cast<const float4*>(src);
            const float4 b4 = *reinterpret_cast<const float4*>(src + 4);
            const int T = key >> 5, r = key & 31;
            const int lr = ((r >> 3) << 2) | (r & 3), st = (r >> 2) & 1;
            const size_t dst = (size_t)b * 524288 + T * 2048 + st * 1024
                             + h * 512 + (((size_t)lg << 4 | lr)) * 8;
            ushort4 h0, l0, h1, l1;
            split_hilo(a.x,  h0.x, l0.x); split_hilo(a.y,  h0.y, l0.y);
            split_hilo(a.z,  h0.z, l0.z); split_hilo(a.w,  h0.w, l0.w);
            split_hilo(b4.x, h1.x, l1.x); split_hilo(b4.y, h1.y, l1.y);
            split_hilo(b4.z, h1.z, l1.z); split_hilo(b4.w, h1.w, l1.w);
            *reinterpret_cast<ushort4*>(Khi + dst)     = h0;
            *reinterpret_cast<ushort4*>(Khi + dst + 4) = h1;
            *reinterpret_cast<ushort4*>(Klo + dst)     = l0;
            *reinterpret_cast<ushort4*>(Klo + dst + 4) = l1;
        }
    } else {
        const int idx = bx - 256;
        const int b = idx / 96, kt = idx % 96;
        const int key0 = kt * 64;
#pragma unroll
        for (int it = 0; it < 4; ++it) {
            const int id = it * 256 + tid;                    // 0..1023
            const int row = id >> 4, c4 = (id & 15) << 2;
            const float4 v = *reinterpret_cast<const float4*>(
                &Vc[((size_t)b * LCACHE + key0 + row) * 64 + c4]);
            sT[c4+0][row] = f2bf(v.x); sT[c4+1][row] = f2bf(v.y);
            sT[c4+2][row] = f2bf(v.z); sT[c4+3][row] = f2bf(v.w);
        }
        __syncthreads();
#pragma unroll
        for (int it = 0; it < 2; ++it) {
            const int s = it * 256 + tid;                     // 0..511
            const int Tl = s >> 8, dt = (s >> 6) & 3, ln = s & 63;
            const int lr = ln & 15, lg = ln >> 4;
            const int kb = Tl * 32 + lg * 8;                  // key within 64-blk
            ushort4 o0, o1;
            o0.x = sT[dt*16+lr][kb+0]; o0.y = sT[dt*16+lr][kb+1];
            o0.z = sT[dt*16+lr][kb+2]; o0.w = sT[dt*16+lr][kb+3];
            o1.x = sT[dt*16+lr][kb+4]; o1.y = sT[dt*16+lr][kb+5];
            o1.z = sT[dt*16+lr][kb+6]; o1.w = sT[dt*16+lr][kb+7];
            const size_t dst = (size_t)b * 524288 + ((key0 >> 5) + Tl) * 2048
                             + dt * 512 + ln * 8;
            *reinterpret_cast<ushort4*>(VtS + dst)     = o0;
            *reinterpret_cast<ushort4*>(VtS + dst + 4) = o1;
        }
    }
}

// ---------------------------------------------------------------------------
// proj_body: MFMA NT GEMM, C = B @ A^T + bias, 512^3, bf16 hi/lo 3-term.
// A,B read from GEMM-frag layouts (all loads lane-contiguous 1KB/instr).
// mode 0: Q  (xQSCALE, hi/lo flat [b][2048][64])
// mode 1: K  (hi/lo -> K swizzled, keys 6144..8191)
// mode 2: V  (bf16 -> VtS swizzled, keys 6144..8191)
// mode 3: O  (fp32 -> df [512][512])
// ---------------------------------------------------------------------------
__device__ __forceinline__ void proj_body(
    const ushort* __restrict__ AhF, const ushort* __restrict__ AlF,
    const ushort* __restrict__ BhF, const ushort* __restrict__ BlF,
    const float* __restrict__ bias, const int mode,
    ushort* __restrict__ d1, ushort* __restrict__ d2, float* __restrict__ df)
{
    const int tid = threadIdx.x;
    const int wv = tid >> 6, lane = tid & 63;
    const int lr = lane & 15, lg = lane >> 4;
    const int m0 = blockIdx.y * 64 + (wv & 1) * 32;   // token base
    const int n0 = blockIdx.x * 64 + (wv >> 1) * 32;  // output-dim base
    const int mT = m0 >> 4, nT = n0 >> 4;

    f32x4 acc[2][2];
#pragma unroll
    for (int mi = 0; mi < 2; ++mi)
#pragma unroll
        for (int ni = 0; ni < 2; ++ni) acc[mi][ni] = (f32x4){0.f, 0.f, 0.f, 0.f};

    const ushort* Ah = AhF + (size_t)nT * 8192 + lane * 8;
    const ushort* Al = AlF + (size_t)nT * 8192 + lane * 8;
    const ushort* Bh = BhF + (size_t)mT * 8192 + lane * 8;
    const ushort* Bl = BlF + (size_t)mT * 8192 + lane * 8;

#pragma unroll 4
    for (int kk = 0; kk < 16; ++kk) {
        bf16x8 ah[2], al[2], bh[2], bl[2];
#pragma unroll
        for (int t = 0; t < 2; ++t) {
            ah[t] = *reinterpret_cast<const bf16x8*>(Ah + t * 8192 + kk * 512);
            al[t] = *reinterpret_cast<const bf16x8*>(Al + t * 8192 + kk * 512);
            bh[t] = *reinterpret_cast<const bf16x8*>(Bh + t * 8192 + kk * 512);
            bl[t] = *reinterpret_cast<const bf16x8*>(Bl + t * 8192 + kk * 512);
        }
        __builtin_amdgcn_s_setprio(1);
#pragma unroll
        for (int mi = 0; mi < 2; ++mi)
#pragma unroll
            for (int ni = 0; ni < 2; ++ni) {
                acc[mi][ni] = __builtin_amdgcn_mfma_f32_16x16x32_bf16(ah[ni], bh[mi], acc[mi][ni], 0, 0, 0);
                acc[mi][ni] = __builtin_amdgcn_mfma_f32_16x16x32_bf16(ah[ni], bl[mi], acc[mi][ni], 0, 0, 0);
                acc[mi][ni] = __builtin_amdgcn_mfma_f32_16x16x32_bf16(al[ni], bh[mi], acc[mi][ni], 0, 0, 0);
            }
        __builtin_amdgcn_s_setprio(0);
    }

#pragma unroll
    for (int mi = 0; mi < 2; ++mi)
#pragma unroll
        for (int ni = 0; ni < 2; ++ni) {
            const int tok = m0 + mi * 16 + lr;
            const int e   = n0 + ni * 16 + lg * 4;
            const float4 bb4 = *reinterpret_cast<const float4*>(&bias[e]);
            float v0 = acc[mi][ni].x + bb4.x, v1 = acc[mi][ni].y + bb4.y;
            float v2 = acc[mi][ni].z + bb4.z, v3 = acc[mi][ni].w + bb4.w;
            const int bb = tok >> 8, s = tok & 255;
            if (mode == 0) {
                v0 *= QSCALE; v1 *= QSCALE; v2 *= QSCALE; v3 *= QSCALE;
                ushort4 h, l;
                split_hilo(v0, h.x, l.x); split_hilo(v1, h.y, l.y);
                split_hilo(v2, h.z, l.z); split_hilo(v3, h.w, l.w);
                const size_t off = (size_t)bb * 131072 + s * 512 + e;
                *reinterpret_cast<ushort4*>(d1 + off) = h;
                *reinterpret_cast<ushort4*>(d2 + off) = l;
            } else if (mode == 1) {
                const int key = LCACHE + s * 8 + (e >> 6);
                const int d0 = e & 63;
                const int T = key >> 5, r = key & 31;
                const int klr = ((r >> 3) << 2) | (r & 3), st = (r >> 2) & 1;
                const int h = d0 >> 5, lg2 = (d0 >> 3) & 3, j0 = d0 & 7;
                const size_t dst = (size_t)bb * 524288 + T * 2048 + st * 1024
                                 + h * 512 + ((lg2 << 4) | klr) * 8 + j0;
                ushort4 hh, ll;
                split_hilo(v0, hh.x, ll.x); split_hilo(v1, hh.y, ll.y);
                split_hilo(v2, hh.z, ll.z); split_hilo(v3, hh.w, ll.w);
                *reinterpret_cast<ushort4*>(d1 + dst) = hh;
                *reinterpret_cast<ushort4*>(d2 + dst) = ll;
            } else if (mode == 2) {
                const int key = LCACHE + s * 8 + (e >> 6);
                const int Tv = key >> 5;
                const int lg3 = (key & 31) >> 3, j = key & 7;
                const float vals[4] = {v0, v1, v2, v3};
#pragma unroll
                for (int c = 0; c < 4; ++c) {
                    const int d = (e & 63) + c;
                    const int dt = d >> 4, vlr = d & 15;
                    d1[(size_t)bb * 524288 + Tv * 2048 + dt * 512
                       + ((lg3 << 4) | vlr) * 8 + j] = f2bf(vals[c]);
                }
            } else {
                float4 o; o.x = v0; o.y = v1; o.z = v2; o.w = v3;
                *reinterpret_cast<float4*>(df + (size_t)tok * 512 + e) = o;
            }
        }
}

__global__ __launch_bounds__(256) void proj_qkv_mfma(
    const ushort* __restrict__ Wqh, const ushort* __restrict__ Wql,
    const ushort* __restrict__ Wkh, const ushort* __restrict__ Wkl,
    const ushort* __restrict__ Wvh, const ushort* __restrict__ Wvl,
    const ushort* __restrict__ xh,  const ushort* __restrict__ xl,
    const float* __restrict__ bq, const float* __restrict__ bk, const float* __restrict__ bv,
    ushort* __restrict__ Qhi, ushort* __restrict__ Qlo,
    ushort* __restrict__ Khi, ushort* __restrict__ Klo,
    ushort* __restrict__ VtS)
{
    if (blockIdx.z == 0)      proj_body(Wqh, Wql, xh, xl, bq, 0, Qhi, Qlo, nullptr);
    else if (blockIdx.z == 1) proj_body(Wkh, Wkl, xh, xl, bk, 1, Khi, Klo, nullptr);
    else                      proj_body(Wvh, Wvl, xh, xl, bv, 2, VtS, nullptr, nullptr);
}

__global__ __launch_bounds__(256) void proj_o_mfma(
    const ushort* __restrict__ Woh, const ushort* __restrict__ Wol,
    const ushort* __restrict__ Aoh, const ushort* __restrict__ Aol,
    const float* __restrict__ bo, float* __restrict__ out)
{
    proj_body(Woh, Wol, Aoh, Aol, bo, 3, nullptr, nullptr, out);
}

// ---------------------------------------------------------------------------
// attn_mfma: flash attention, r3 geometry (grid (4,64,2), 4 waves, 512-key
// chunk/wave, 32 q-rows/block) with swizzled contiguous loads + prefetch.
// ---------------------------------------------------------------------------
#define ALOAD(kf, lf, vf, t) do {                                                   \
    _Pragma("unroll")                                                               \
    for (int st = 0; st < 2; ++st) {                                                \
        _Pragma("unroll")                                                           \
        for (int h = 0; h < 2; ++h) {                                               \
            kf[st][h] = *reinterpret_cast<const bf16x8*>(kh_p + (t) * 2048 + st * 1024 + h * 512); \
            lf[st][h] = *reinterpret_cast<const bf16x8*>(kl_p + (t) * 2048 + st * 1024 + h * 512); \
        }                                                                           \
    }                                                                               \
    _Pragma("unroll")                                                               \
    for (int dt = 0; dt < 4; ++dt)                                                  \
        vf[dt] = *reinterpret_cast<const bf16x8*>(vt_p + (t) * 2048 + dt * 512);    \
} while (0)

#define ACOMP(kf, lf, vf) do {                                                      \
    _Pragma("unroll")                                                               \
    for (int q = 0; q < 2; ++q) {                                                   \
        f32x4 s0 = {0.f,0.f,0.f,0.f}, s1 = {0.f,0.f,0.f,0.f};                       \
        __builtin_amdgcn_s_setprio(1);                                              \
        _Pragma("unroll")                                                           \
        for (int h = 0; h < 2; ++h) {                                               \
            s0 = __builtin_amdgcn_mfma_f32_16x16x32_bf16(kf[0][h], qh[q][h], s0, 0, 0, 0); \
            s0 = __builtin_amdgcn_mfma_f32_16x16x32_bf16(kf[0][h], ql[q][h], s0, 0, 0, 0); \
            s0 = __builtin_amdgcn_mfma_f32_16x16x32_bf16(lf[0][h], qh[q][h], s0, 0, 0, 0); \
            s1 = __builtin_amdgcn_mfma_f32_16x16x32_bf16(kf[1][h], qh[q][h], s1, 0, 0, 0); \
            s1 = __builtin_amdgcn_mfma_f32_16x16x32_bf16(kf[1][h], ql[q][h], s1, 0, 0, 0); \
            s1 = __builtin_amdgcn_mfma_f32_16x16x32_bf16(lf[1][h], qh[q][h], s1, 0, 0, 0); \
        }                                                                           \
        __builtin_amdgcn_s_setprio(0);                                              \
        float& mq = q ? m1 : m0;                                                    \
        float& lq = q ? l1 : l0;                                                    \
        float tm = fmaxf(fmaxf(fmaxf(s0.x, s0.y), fmaxf(s0.z, s0.w)),               \
                         fmaxf(fmaxf(s1.x, s1.y), fmaxf(s1.z, s1.w)));              \
        tm = fmaxf(tm, __shfl_xor(tm, 16));                                         \
        tm = fmaxf(tm, __shfl_xor(tm, 32));                                         \
        const float mn = fmaxf(mq, tm);                                             \
        const float corr = __builtin_exp2f(mq - mn);                                \
        float p[8];                                                                 \
        p[0] = __builtin_exp2f(s0.x - mn); p[1] = __builtin_exp2f(s0.y - mn);       \
        p[2] = __builtin_exp2f(s0.z - mn); p[3] = __builtin_exp2f(s0.w - mn);       \
        p[4] = __builtin_exp2f(s1.x - mn); p[5] = __builtin_exp2f(s1.y - mn);       \
        p[6] = __builtin_exp2f(s1.z - mn); p[7] = __builtin_exp2f(s1.w - mn);       \
        float ps = ((p[0]+p[1]) + (p[2]+p[3])) + ((p[4]+p[5]) + (p[6]+p[7]));       \
        ps += __shfl_xor(ps, 16);                                                   \
        ps += __shfl_xor(ps, 32);                                                   \
        lq = lq * corr + ps; mq = mn;                                               \
        union { bf16x8 v; ushort u[8]; } pf;                                        \
        _Pragma("unroll")                                                           \
        for (int j = 0; j < 8; ++j) pf.u[j] = f2bf(p[j]);                           \
        __builtin_amdgcn_s_setprio(1);                                              \
        _Pragma("unroll")                                                           \
        for (int dt = 0; dt < 4; ++dt) {                                            \
            f32x4 a = acc[q][dt];                                                   \
            a.x *= corr; a.y *= corr; a.z *= corr; a.w *= corr;                     \
            acc[q][dt] = __builtin_amdgcn_mfma_f32_16x16x32_bf16(vf[dt], pf.v, a, 0, 0, 0); \
        }                                                                           \
        __builtin_amdgcn_s_setprio(0);                                              \
    }                                                                               \
} while (0)

__global__ __launch_bounds__(256) void attn_mfma(
    const ushort* __restrict__ Qhi, const ushort* __restrict__ Qlo,
    const ushort* __restrict__ Khi, const ushort* __restrict__ Klo,
    const ushort* __restrict__ VtS,
    float* __restrict__ Pacc, float* __restrict__ Pm, float* __restrict__ Pl)
{
    __shared__ float sAcc[4][32][68];
    __shared__ float sM[4][32];
    __shared__ float sL[4][32];

    const int tid = threadIdx.x;
    const int wv = tid >> 6, lane = tid & 63;
    const int lr = lane & 15, lg = lane >> 4;
    const int split = blockIdx.x, qb = blockIdx.y, b = blockIdx.z;

    bf16x8 qh[2][2], ql[2][2];
    {
        const int qrow0 = b * 2048 + qb * 32 + lr;
#pragma unroll
        for (int q = 0; q < 2; ++q)
#pragma unroll
            for (int h = 0; h < 2; ++h) {
                const int off = (qrow0 + q * 16) * 64 + h * 32 + lg * 8;
                qh[q][h] = *reinterpret_cast<const bf16x8*>(Qhi + off);
                ql[q][h] = *reinterpret_cast<const bf16x8*>(Qlo + off);
            }
    }

    const int T0 = split * 64 + wv * 16;          // 16 tiles of 32 keys/wave
    const ushort* kh_p = Khi + (size_t)b * 524288 + (size_t)T0 * 2048 + lane * 8;
    const ushort* kl_p = Klo + (size_t)b * 524288 + (size_t)T0 * 2048 + lane * 8;
    const ushort* vt_p = VtS + (size_t)b * 524288 + (size_t)T0 * 2048 + lane * 8;

    f32x4 acc[2][4];
#pragma unroll
    for (int q = 0; q < 2; ++q)
#pragma unroll
        for (int dt = 0; dt < 4; ++dt) acc[q][dt] = (f32x4){0.f, 0.f, 0.f, 0.f};
    float m0 = -INFINITY, m1 = -INFINITY, l0 = 0.f, l1 = 0.f;

    bf16x8 kfA[2][2], lfA[2][2], vfA[4];
    bf16x8 kfB[2][2], lfB[2][2], vfB[4];

    ALOAD(kfA, lfA, vfA, 0);
    for (int tt = 0; tt < 8; ++tt) {              // 16 tiles, 2 per iter
        ALOAD(kfB, lfB, vfB, 2 * tt + 1);
        ACOMP(kfA, lfA, vfA);
        if (tt < 7) ALOAD(kfA, lfA, vfA, 2 * tt + 2);
        ACOMP(kfB, lfB, vfB);
    }

    // per-wave partials -> LDS   (C/D: col=lane&15 -> qrow, rows -> dims)
#pragma unroll
    for (int q = 0; q < 2; ++q)
#pragma unroll
        for (int dt = 0; dt < 4; ++dt) {
            float4 o; o.x = acc[q][dt].x; o.y = acc[q][dt].y; o.z = acc[q][dt].z; o.w = acc[q][dt].w;
            *reinterpret_cast<float4*>(&sAcc[wv][q * 16 + lr][dt * 16 + lg * 4]) = o;
        }
    if (lg == 0) {
        sM[wv][lr] = m0;      sM[wv][16 + lr] = m1;
        sL[wv][lr] = l0;      sL[wv][16 + lr] = l1;
    }
    __syncthreads();

    // combine 4 waves: thread -> (qrow = tid>>3, 8 dims at dg*8)
    {
        const int qrow = tid >> 3, dg = tid & 7;
        float mw[4], ms = -INFINITY;
#pragma unroll
        for (int w = 0; w < 4; ++w) { mw[w] = sM[w][qrow]; ms = fmaxf(ms, mw[w]); }
        float den = 0.f;
        float num[8] = {};
#pragma unroll
        for (int w = 0; w < 4; ++w) {
            const float e = __builtin_exp2f(mw[w] - ms);
            den = fmaf(sL[w][qrow], e, den);
            const float4 a0 = *reinterpret_cast<const float4*>(&sAcc[w][qrow][dg * 8]);
            const float4 a1 = *reinterpret_cast<const float4*>(&sAcc[w][qrow][dg * 8 + 4]);
            num[0] = fmaf(a0.x, e, num[0]); num[1] = fmaf(a0.y, e, num[1]);
            num[2] = fmaf(a0.z, e, num[2]); num[3] = fmaf(a0.w, e, num[3]);
            num[4] = fmaf(a1.x, e, num[4]); num[5] = fmaf(a1.y, e, num[5]);
            num[6] = fmaf(a1.z, e, num[6]); num[7] = fmaf(a1.w, e, num[7]);
        }
        const int row_g = b * 2048 + qb * 32 + qrow;
        float* dst = Pacc + ((size_t)row_g * NSPLIT + split) * 64 + dg * 8;
        float4 o0 = {num[0], num[1], num[2], num[3]};
        float4 o1 = {num[4], num[5], num[6], num[7]};
        *reinterpret_cast<float4*>(dst)     = o0;
        *reinterpret_cast<float4*>(dst + 4) = o1;
        if (dg == 0) {
            Pm[(size_t)row_g * NSPLIT + split] = ms;
            Pl[(size_t)row_g * NSPLIT + split] = den;
        }
    }
}

// Combine the NSPLIT partials per q-row; emit Ao hi/lo in GEMM-frag layout.
__global__ __launch_bounds__(256) void combine2(
    const float* __restrict__ Pacc, const float* __restrict__ Pm,
    const float* __restrict__ Pl, ushort* __restrict__ Aoh, ushort* __restrict__ Aol)
{
    const int g = blockIdx.x * 256 + threadIdx.x;   // 0..32767
    const int row = g >> 3, d0 = (g & 7) * 8;
    float mv[NSPLIT], ms = -INFINITY;
#pragma unroll
    for (int sp = 0; sp < NSPLIT; ++sp) { mv[sp] = Pm[row * NSPLIT + sp]; ms = fmaxf(ms, mv[sp]); }
    float den = 0.f;
    float num[8] = {};
#pragma unroll
    for (int sp = 0; sp < NSPLIT; ++sp) {
        const float e = __builtin_exp2f(mv[sp] - ms);
        den = fmaf(Pl[row * NSPLIT + sp], e, den);
        const float* src = Pacc + ((size_t)row * NSPLIT + sp) * 64 + d0;
        const float4 a0 = *reinterpret_cast<const float4*>(src);
        const float4 a1 = *reinterpret_cast<const float4*>(src + 4);
        num[0] = fmaf(a0.x, e, num[0]); num[1] = fmaf(a0.y, e, num[1]);
        num[2] = fmaf(a0.z, e, num[2]); num[3] = fmaf(a0.w, e, num[3]);
        num[4] = fmaf(a1.x, e, num[4]); num[5] = fmaf(a1.y, e, num[5]);
        num[6] = fmaf(a1.z, e, num[6]); num[7] = fmaf(a1.w, e, num[7]);
    }
    const float inv = 1.0f / den;
    const int bb = row >> 11, qr = row & 2047;
    const int tok = bb * 256 + (qr >> 3);           // global token 0..511
    const int e = (qr & 7) * 64 + d0;               // e&7 == 0
    const int R = tok >> 4, lrr = tok & 15, kk = e >> 5, lgg = (e >> 3) & 3;
    const size_t dst = (size_t)R * 8192 + kk * 512 + ((lgg << 4) | lrr) * 8;
    ushort4 h0, l0, h1, l1;
    split_hilo(num[0]*inv, h0.x, l0.x); split_hilo(num[1]*inv, h0.y, l0.y);
    split_hilo(num[2]*inv, h0.z, l0.z); split_hilo(num[3]*inv, h0.w, l0.w);
    split_hilo(num[4]*inv, h1.x, l1.x); split_hilo(num[5]*inv, h1.y, l1.y);
    split_hilo(num[6]*inv, h1.z, l1.z); split_hilo(num[7]*inv, h1.w, l1.w);
    *reinterpret_cast<ushort4*>(Aoh + dst)     = h0;
    *reinterpret_cast<ushort4*>(Aoh + dst + 4) = h1;
    *reinterpret_cast<ushort4*>(Aol + dst)     = l0;
    *reinterpret_cast<ushort4*>(Aol + dst + 4) = l1;
}

// ---------------------------------------------------------------------------
extern "C" void kernel_launch(void* const* d_in, const int* in_sizes, int n_in,
                              void* d_out, int out_size, void* d_ws, size_t ws_size,
                              hipStream_t stream)
{
    const float* x  = (const float*)d_in[0];
    const float* kc = (const float*)d_in[1];
    const float* vc = (const float*)d_in[2];
    const float* Wq = (const float*)d_in[3];
    const float* bq = (const float*)d_in[4];
    const float* Wk = (const float*)d_in[5];
    const float* bk = (const float*)d_in[6];
    const float* Wv = (const float*)d_in[7];
    const float* bv = (const float*)d_in[8];
    const float* Wo = (const float*)d_in[9];
    const float* bo = (const float*)d_in[10];
    float* out = (float*)d_out;

    ushort* us  = (ushort*)d_ws;
    ushort* Khi = us;                   // 1048576
    ushort* Klo = us + 1048576;         // 1048576
    ushort* VtS = us + 2097152;         // 1048576
    ushort* Qhi = us + 3145728;         //  262144
    ushort* Qlo = us + 3407872;
    ushort* xh  = us + 3670016;
    ushort* xl  = us + 3932160;
    ushort* Wqh = us + 4194304;
    ushort* Wql = us + 4456448;
    ushort* Wkh = us + 4718592;
    ushort* Wkl = us + 4980736;
    ushort* Wvh = us + 5242880;
    ushort* Wvl = us + 5505024;
    ushort* Woh = us + 5767168;
    ushort* Wol = us + 6029312;
    ushort* Aoh = us + 6291456;
    ushort* Aol = us + 6553600;         // ends 6815744 us (13.6 MB)
    float*  fs  = (float*)(us + 6815744);
    float*  Pacc = fs;                  // 1048576 f
    float*  Pm   = fs + 1048576;        //   16384 f
    float*  Pl   = fs + 1064960;        //   16384 f  -> ~18 MB total

    // 1. prep: frag-layout hi/lo conversions + K-cache swizzle + V-cache swizzle
    prep_all<<<dim3(448), 256, 0, stream>>>(
        x, Wq, Wk, Wv, Wo, kc, vc,
        xh, xl, Wqh, Wql, Wkh, Wkl, Wvh, Wvl, Woh, Wol, Khi, Klo, VtS);

    // 2. QKV projections (MFMA, frag-layout inputs)
    proj_qkv_mfma<<<dim3(8, 8, 3), 256, 0, stream>>>(
        Wqh, Wql, Wkh, Wkl, Wvh, Wvl, xh, xl, bq, bk, bv, Qhi, Qlo, Khi, Klo, VtS);

    // 3. Flash attention partials (swizzled contiguous loads)
    attn_mfma<<<dim3(NSPLIT, 64, B_), 256, 0, stream>>>(
        Qhi, Qlo, Khi, Klo, VtS, Pacc, Pm, Pl);

    // 4. Combine L-splits -> Ao (frag layout, hi/lo)
    combine2<<<dim3(128), 256, 0, stream>>>(Pacc, Pm, Pl, Aoh, Aol);

    // 5. Output projection (MFMA) -> fp32 out
    proj_o_mfma<<<dim3(8, 8), 256, 0, stream>>>(Woh, Wol, Aoh, Aol, bo, out);
}